// Round 3
// baseline (171.339 us; speedup 1.0000x reference)
//
#include <hip/hip_runtime.h>

// Problem constants (match reference setup_inputs / module constants)
#define NV 64          // NUM_VARIANTS
#define NB 1024        // B
#define NH 24          // H
#define STEPS 16       // MCMC_STEPS
#define STEP_SIZE 0.1f
#define BETA 0.1f
#define EPSL 1e-7f

constexpr int BH = NB * NH;        // 24576
constexpr int N  = NV * BH;        // 1,572,864 elements per step
// output: [STEPS, NV, NB, NH, 1] = 25,165,824 floats

// Native clang vector types (required by __builtin_nontemporal_store;
// HIP's float4 is a class and is rejected).
typedef float  fx4 __attribute__((ext_vector_type(4)));
typedef int    ix4 __attribute__((ext_vector_type(4)));

// Single fused kernel:
//   grad wrt preds[v,b,h] of total_energy is purely local (features/W_feat/b
//   contribute an additive constant with zero grad):
//     g = mask^2/(horses[b]*V*B) * p(1-p) * (w_prob - beta*de/dp),  p = sigmoid(x)
//     de/dp = -(log(p+eps) + p/(p+eps) - log(1-p+eps) - (1-p)/(1-p+eps))
//   16 steps iterated in registers, one nontemporal 16B store per step.
__global__ __launch_bounds__(256) void mcmc_kernel(const float* __restrict__ preds,
                                                   const int* __restrict__ mask,
                                                   const float* __restrict__ w_prob,
                                                   float* __restrict__ out) {
    int t = blockIdx.x * blockDim.x + threadIdx.x;
    int i0 = t * 4;
    if (i0 >= N) return;
    int bh = i0 % BH;            // BH % 4 == 0 so bh is 16B-aligned
    int b  = bh / NH;
    int h0 = bh % NH;            // NH=24, i0%4==0 -> h0 in {0,4,...,20}, never crosses b

    // horses[b] = sum of mask row (24 ints, 16B-aligned, L2-resident: 96 KB total)
    const int* mrow = mask + b * NH;
    float horses = 0.0f;
#pragma unroll
    for (int k = 0; k < NH / 4; ++k) {
        ix4 mv = *reinterpret_cast<const ix4*>(mrow + 4 * k);
        horses += (float)(mv.x + mv.y + mv.z + mv.w);
    }
    float inv = (horses != 0.0f) ? 1.0f / (horses * (float)(NV * NB)) : 0.0f;

    float sc[4];
#pragma unroll
    for (int j = 0; j < 4; ++j) {
        float m = (float)mrow[h0 + j];
        sc[j] = m * m * inv * STEP_SIZE;   // premultiplied by step size
    }

    const float wp = w_prob[0];
    fx4 xv = *reinterpret_cast<const fx4*>(preds + i0);
    float x[4] = {xv.x, xv.y, xv.z, xv.w};

    for (int s = 0; s < STEPS; ++s) {
#pragma unroll
        for (int j = 0; j < 4; ++j) {
            float p = __fdividef(1.0f, 1.0f + __expf(-x[j]));
            float pp = p * (1.0f - p);                     // dp/dx
            // de/dp of entropy e(p) = -(p log(p+eps) + (1-p) log(1-p+eps))
            float dedp = -(__logf(p + EPSL) + __fdividef(p, p + EPSL)
                           - __logf(1.0f - p + EPSL)
                           - __fdividef(1.0f - p, 1.0f - p + EPSL));
            float g = pp * (wp - BETA * dedp);
            x[j] -= sc[j] * g;
        }
        fx4 o = {x[0], x[1], x[2], x[3]};
        __builtin_nontemporal_store(o, reinterpret_cast<fx4*>(out + (size_t)s * N + i0));
    }
}

extern "C" void kernel_launch(void* const* d_in, const int* in_sizes, int n_in,
                              void* d_out, int out_size, void* d_ws, size_t ws_size,
                              hipStream_t stream) {
    // inputs: 0=features[B,H,D] (UNUSED: zero gradient), 1=predictions_init[V,B,H],
    //         2=W_feat[D] (UNUSED), 3=w_prob[1], 4=b[1] (UNUSED), 5=attention_mask[B,H]
    const float* preds  = (const float*)d_in[1];
    const float* w_prob = (const float*)d_in[3];
    const int*   mask   = (const int*)d_in[5];
    float* out = (float*)d_out;

    int threads = N / 4;                 // 393,216
    int blocks = (threads + 255) / 256;  // 1536
    mcmc_kernel<<<blocks, 256, 0, stream>>>(preds, mask, w_prob, out);
}

// Round 4
// 139.668 us; speedup vs baseline: 1.2268x; 1.2268x over previous
//
#include <hip/hip_runtime.h>

// Problem constants (match reference setup_inputs / module constants)
#define NV 64          // NUM_VARIANTS
#define NB 1024        // B
#define NH 24          // H
#define STEPS 16       // MCMC_STEPS
#define STEP_SIZE 0.1f
#define BETA 0.1f

constexpr int BH = NB * NH;        // 24576
constexpr int N  = NV * BH;        // 1,572,864 elements per step
// output: [STEPS, NV, NB, NH, 1] = 25,165,824 floats

// Native clang vector types (HIP float4 is a class; use ext_vector_type)
typedef float  fx4 __attribute__((ext_vector_type(4)));
typedef int    ix4 __attribute__((ext_vector_type(4)));

// grad wrt preds[v,b,h] of total_energy is purely local (features/W_feat/b
// are additive constants with zero grad):
//   g = mask^2/(horses[b]*V*B) * p(1-p) * (wp - beta*de/dp),  p = sigmoid(x)
// de/dp = -(log(p+eps) + p/(p+eps) - log(1-p+eps) - (1-p)/(1-p+eps))
//       = -(log p - log(1-p)) + O(eps^2)   [eps terms cancel to 1st order]
//       = -logit(p) = -x
// so  g = p(1-p) * (wp + beta*x)  -- 1 exp + 1 rcp per element-step, no logs.
// Note 1-p = e*p with e = exp(-x), so p(1-p) = p*p*e.
__global__ __launch_bounds__(256) void mcmc_kernel(const float* __restrict__ preds,
                                                   const int* __restrict__ mask,
                                                   const float* __restrict__ w_prob,
                                                   float* __restrict__ out) {
    int t = blockIdx.x * blockDim.x + threadIdx.x;
    int i0 = t * 4;
    if (i0 >= N) return;
    int bh = i0 % BH;            // BH % 4 == 0 so bh is 16B-aligned
    int b  = bh / NH;
    int h0 = bh % NH;            // NH=24, i0%4==0 -> h0 in {0,4,...,20}, never crosses b

    // horses[b] = sum of mask row (24 ints, L2-resident: 96 KB total)
    const int* mrow = mask + b * NH;
    float horses = 0.0f;
#pragma unroll
    for (int k = 0; k < NH / 4; ++k) {
        ix4 mv = *reinterpret_cast<const ix4*>(mrow + 4 * k);
        horses += (float)(mv.x + mv.y + mv.z + mv.w);
    }
    float inv = (horses != 0.0f) ? 1.0f / (horses * (float)(NV * NB)) : 0.0f;

    float sc[4];
#pragma unroll
    for (int j = 0; j < 4; ++j) {
        float m = (float)mrow[h0 + j];
        sc[j] = m * m * inv * STEP_SIZE;   // premultiplied by step size
    }

    const float wp = w_prob[0];
    fx4 xv = *reinterpret_cast<const fx4*>(preds + i0);
    float x[4] = {xv.x, xv.y, xv.z, xv.w};

    for (int s = 0; s < STEPS; ++s) {
#pragma unroll
        for (int j = 0; j < 4; ++j) {
            float e  = __expf(-x[j]);                    // v_exp (src modifier -)
            float p  = __frcp_rn(1.0f + e);              // p = sigmoid(x)
            float pp = p * p * e;                        // p(1-p) since 1-p = e*p
            float tt = fmaf(BETA, x[j], wp);             // wp + beta*x
            x[j] = fmaf(-sc[j], pp * tt, x[j]);          // x -= sc * p(1-p)(wp+beta*x)
        }
        fx4 o = {x[0], x[1], x[2], x[3]};
        // plain (cached) store: 100.7 MB output fits the 256 MB Infinity Cache
        *reinterpret_cast<fx4*>(out + (size_t)s * N + i0) = o;
    }
}

extern "C" void kernel_launch(void* const* d_in, const int* in_sizes, int n_in,
                              void* d_out, int out_size, void* d_ws, size_t ws_size,
                              hipStream_t stream) {
    // inputs: 0=features[B,H,D] (UNUSED: zero gradient), 1=predictions_init[V,B,H],
    //         2=W_feat[D] (UNUSED), 3=w_prob[1], 4=b[1] (UNUSED), 5=attention_mask[B,H]
    const float* preds  = (const float*)d_in[1];
    const float* w_prob = (const float*)d_in[3];
    const int*   mask   = (const int*)d_in[5];
    float* out = (float*)d_out;

    int threads = N / 4;                 // 393,216
    int blocks = (threads + 255) / 256;  // 1536
    mcmc_kernel<<<blocks, 256, 0, stream>>>(preds, mask, w_prob, out);
}